// Round 9
// baseline (665.870 us; speedup 1.0000x reference)
//
#include <hip/hip_runtime.h>
#include <math.h>

#define LOG2E 1.4426950408889634f

#if __has_builtin(__builtin_amdgcn_exp2f)
#define EXP2(x) __builtin_amdgcn_exp2f(x)
#else
#define EXP2(x) exp2f(x)
#endif

constexpr int B_ = 4, N_ = 2048, H_ = 4, D_ = 32, HD_ = 128;
constexpr int BH_ = B_ * H_;          // 16
constexpr int ROWS_ = BH_ * N_;       // 32768
constexpr size_t M_ = (size_t)ROWS_ * D_;  // 1,048,576 floats

typedef float v4f __attribute__((ext_vector_type(4)));
typedef _Float16 h2 __attribute__((ext_vector_type(2)));

static __device__ __forceinline__ h2 habs2(h2 z) {
    unsigned int t = __builtin_bit_cast(unsigned int, z) & 0x7FFF7FFFu;
    return __builtin_bit_cast(h2, t);
}
static __device__ __forceinline__ h2 hadd2u(unsigned int a, unsigned int b) {
    return __builtin_bit_cast(h2, a) + __builtin_bit_cast(h2, b);  // v_pk_add_f16
}
static __device__ __forceinline__ h2 u2h(unsigned int a) {
    return __builtin_bit_cast(h2, a);
}

// x[BN,K] @ Wl/Wr[K,128] + bl/br ->
//   xl   f32 [bh][n][d]      (k_u only)
//   xlh  f16 [bh][n][d]      (score)
//   xrh  f16 [bh][n][d]      (per-lane target rows)
//   xlpT f16 [bh][n/2][d]    (PV: j-pairs per d)
__global__ __launch_bounds__(256) void k_linear(
    const float* __restrict__ x,
    const float* __restrict__ Wl, const float* __restrict__ bl,
    const float* __restrict__ Wr, const float* __restrict__ br,
    float* __restrict__ xl, unsigned short* __restrict__ xlh,
    unsigned short* __restrict__ xrh, unsigned int* __restrict__ xlpT, int K)
{
    __shared__ __align__(16) float xs[32 * 128];
    const int tid = threadIdx.x;
    const int r0 = blockIdx.x * 32;
    const float4* src = (const float4*)(x + (size_t)r0 * K);
    float4* dst = (float4*)xs;
    for (int idx = tid; idx < 8 * K; idx += 256) dst[idx] = src[idx];
    __syncthreads();

    const int c  = tid & 127;
    const int rg = tid >> 7;
    float accl[16], accr[16];
    const float blv = bl[c], brv = br[c];
    #pragma unroll
    for (int r = 0; r < 16; r++) { accl[r] = blv; accr[r] = brv; }
    #pragma unroll 8
    for (int k = 0; k < K; k++) {
        const float wl = Wl[k * HD_ + c];
        const float wr = Wr[k * HD_ + c];
        #pragma unroll
        for (int r = 0; r < 16; r++) {
            const float xv = xs[(rg * 16 + r) * K + k];
            accl[r] = fmaf(xv, wl, accl[r]);
            accr[r] = fmaf(xv, wr, accr[r]);
        }
    }
    const int h = c >> 5, d = c & 31;
    #pragma unroll
    for (int r = 0; r < 16; r++) {
        const int row = r0 + rg * 16 + r;
        const int b = row >> 11, n = row & (N_ - 1);
        const size_t o = (((size_t)(b * H_ + h)) * N_ + n) * D_ + d;
        xl[o] = accl[r];
        xlh[o] = __builtin_bit_cast(unsigned short, (_Float16)accl[r]);
        xrh[o] = __builtin_bit_cast(unsigned short, (_Float16)accr[r]);
    }
    #pragma unroll
    for (int r = 0; r < 16; r += 2) {
        const int row = r0 + rg * 16 + r;
        const int b = row >> 11, n = row & (N_ - 1);
        h2 pr;
        pr.x = (_Float16)accl[r];
        pr.y = (_Float16)accl[r + 1];
        const size_t o = (((size_t)(b * H_ + h)) * (N_ / 2) + (n >> 1)) * D_ + d;
        xlpT[o] = __builtin_bit_cast(unsigned int, pr);
    }
}

// u_j = 0.6*log2e * att_h . xl_j  (target-side term cancels in softmax)
__global__ __launch_bounds__(256) void k_u(
    const float* __restrict__ xl, const float* __restrict__ att,
    float* __restrict__ u)
{
    const int idx = blockIdx.x * 256 + threadIdx.x; // [0, ROWS_)
    const int h = (idx / N_) & (H_ - 1);
    const float4* a4 = (const float4*)(att + h * D_);
    const float4* l4 = (const float4*)(xl + (size_t)idx * D_);
    float su = 0.f;
    #pragma unroll
    for (int q = 0; q < 8; q++) {
        const float4 a = a4[q], lv = l4[q];
        su += a.x * lv.x + a.y * lv.y + a.z * lv.z + a.w * lv.w;
    }
    u[idx] = 0.6f * LOG2E * su;
}

// Per-row sound upper bound on e (log2 domain); also packs tch.
__global__ __launch_bounds__(512) void k_bound(
    const unsigned int* __restrict__ xlh, const unsigned int* __restrict__ xrh,
    const float* __restrict__ u, const float* __restrict__ att,
    float* __restrict__ bound, unsigned int* __restrict__ tch)
{
    __shared__ float redA[16][33];
    __shared__ float redB[16][33];
    __shared__ float clv[32];
    __shared__ float tca[32];
    __shared__ float redu[512];
    const int bh = blockIdx.x, h = bh & (H_ - 1), t = threadIdx.x;

    if (bh < H_ && t < 16) {
        h2 v;
        v.x = (_Float16)(att[bh * D_ + 2 * t]     * (0.4f * LOG2E));
        v.y = (_Float16)(att[bh * D_ + 2 * t + 1] * (0.4f * LOG2E));
        tch[bh * 16 + t] = __builtin_bit_cast(unsigned int, v);
    }
    if (t < 16) {
        _Float16 a = (_Float16)(att[h * D_ + 2 * t]     * (0.4f * LOG2E));
        _Float16 b = (_Float16)(att[h * D_ + 2 * t + 1] * (0.4f * LOG2E));
        tca[2 * t]     = fabsf((float)a);
        tca[2 * t + 1] = fabsf((float)b);
    }
    const unsigned int* xb = xlh + (size_t)bh * N_ * 16;
    const int p = t & 15, rg = t >> 4;
    float m0 = 0.f, m1 = 0.f;
    for (int r = rg; r < N_; r += 32) {
        h2 z = __builtin_bit_cast(h2, xb[r * 16 + p] & 0x7FFF7FFFu);
        m0 = fmaxf(m0, (float)z.x);
        m1 = fmaxf(m1, (float)z.y);
    }
    redA[p][rg] = m0; redB[p][rg] = m1;
    const float* ub = u + (size_t)bh * N_;
    float um = -1e30f;
    for (int r = t; r < N_; r += 512) um = fmaxf(um, ub[r]);
    redu[t] = um;
    __syncthreads();
    if (t < 16) {
        float a = 0.f, b = 0.f;
        for (int g = 0; g < 32; g++) { a = fmaxf(a, redA[t][g]); b = fmaxf(b, redB[t][g]); }
        clv[2 * t] = a; clv[2 * t + 1] = b;
    }
    for (int s = 256; s > 0; s >>= 1) {
        if (t < s) redu[t] = fmaxf(redu[t], redu[t + s]);
        __syncthreads();
    }
    const float umax = redu[0];
    const unsigned int* xrb = xrh + (size_t)bh * N_ * 16;
    for (int r = t; r < N_; r += 512) {
        float s = 0.f;
        #pragma unroll
        for (int k = 0; k < 16; k++) {
            h2 z = __builtin_bit_cast(h2, xrb[r * 16 + k] & 0x7FFF7FFFu);
            s += tca[2 * k] * (clv[2 * k] + (float)z.x)
               + tca[2 * k + 1] * (clv[2 * k + 1] + (float)z.y);
        }
        bound[bh * N_ + r] = umax + s + 0.25f;
    }
}

// Flash GATv2 attention, LANE-PAIR d-split (dh = lane&1 owns 16 of 32 dims).
// Live state ~55 VGPRs -> fits the 64-VGPR/8-wave class with NO AGPR
// shuttling (R8 pathology: full-row lanes forced o[32] into AGPRs with
// accvgpr round-trips on every fdot2). Score partials merged with one
// shfl_xor(1) (DPP pair swap); bound-softmax keeps j's independent.
__global__ __launch_bounds__(256) void k_attn(
    const unsigned int* __restrict__ xlh,   // [bh][n][16] u32 (d-pairs)
    const unsigned int* __restrict__ xlpT,  // [bh][n/2][32] u32 (j-pairs)
    const unsigned int* __restrict__ xrh,
    const float* __restrict__ u, const float* __restrict__ bound,
    const unsigned int* __restrict__ tch,
    float* __restrict__ P, float* __restrict__ lb, int jlen)
{
    const int tid = threadIdx.x, lane = tid & 63, wid = tid >> 6;
    const int dh = lane & 1, r = lane >> 1;            // 32 rows per wave
    const int t256 = blockIdx.x & 255, part = blockIdx.x >> 8;
    const int bh = t256 >> 4;
    const int i  = (t256 & 15) * 128 + wid * 32 + r;
    const int h  = bh & (H_ - 1);
    const int row = bh * N_ + i;

    h2 tc[8];
    #pragma unroll
    for (int k = 0; k < 8; k++) tc[k] = u2h(tch[h * 16 + dh * 8 + k]);

    unsigned int xrp[8];
    {
        const uint4* s = (const uint4*)(xrh + (size_t)row * 16 + dh * 8);
        const uint4 a = s[0], b = s[1];
        xrp[0]=a.x; xrp[1]=a.y; xrp[2]=a.z; xrp[3]=a.w;
        xrp[4]=b.x; xrp[5]=b.y; xrp[6]=b.z; xrp[7]=b.w;
    }
    const float negb = -bound[row];

    float l = 0.f;
    float o[16];
    #pragma unroll
    for (int k = 0; k < 16; k++) o[k] = 0.f;

    const unsigned int* xlh_b = xlh + (size_t)bh * N_ * 16;
    const unsigned int* xlt_b = xlpT + (size_t)bh * (N_ / 2) * 32;
    const float* u_b = u + (size_t)bh * N_;

    const int jpb = (part * jlen) >> 1, jpe = jpb + (jlen >> 1);
    for (int jp = jpb; jp < jpe; jp++) {
        const uint4* wp0 = (const uint4*)(xlh_b + (size_t)(2 * jp) * 16 + dh * 8);
        const uint4* wp1 = (const uint4*)(xlh_b + (size_t)(2 * jp) * 16 + 16 + dh * 8);
        const uint4 wa0 = wp0[0], wb0 = wp0[1];
        const uint4 wa1 = wp1[0], wb1 = wp1[1];
        float e0 = 0.f, f0 = 0.f, e1 = 0.f, f1 = 0.f;
        e0 = __builtin_amdgcn_fdot2(habs2(hadd2u(wa0.x, xrp[0])), tc[0], e0, false);
        f0 = __builtin_amdgcn_fdot2(habs2(hadd2u(wa0.y, xrp[1])), tc[1], f0, false);
        e0 = __builtin_amdgcn_fdot2(habs2(hadd2u(wa0.z, xrp[2])), tc[2], e0, false);
        f0 = __builtin_amdgcn_fdot2(habs2(hadd2u(wa0.w, xrp[3])), tc[3], f0, false);
        e0 = __builtin_amdgcn_fdot2(habs2(hadd2u(wb0.x, xrp[4])), tc[4], e0, false);
        f0 = __builtin_amdgcn_fdot2(habs2(hadd2u(wb0.y, xrp[5])), tc[5], f0, false);
        e0 = __builtin_amdgcn_fdot2(habs2(hadd2u(wb0.z, xrp[6])), tc[6], e0, false);
        f0 = __builtin_amdgcn_fdot2(habs2(hadd2u(wb0.w, xrp[7])), tc[7], f0, false);
        e1 = __builtin_amdgcn_fdot2(habs2(hadd2u(wa1.x, xrp[0])), tc[0], e1, false);
        f1 = __builtin_amdgcn_fdot2(habs2(hadd2u(wa1.y, xrp[1])), tc[1], f1, false);
        e1 = __builtin_amdgcn_fdot2(habs2(hadd2u(wa1.z, xrp[2])), tc[2], e1, false);
        f1 = __builtin_amdgcn_fdot2(habs2(hadd2u(wa1.w, xrp[3])), tc[3], f1, false);
        e1 = __builtin_amdgcn_fdot2(habs2(hadd2u(wb1.x, xrp[4])), tc[4], e1, false);
        f1 = __builtin_amdgcn_fdot2(habs2(hadd2u(wb1.y, xrp[5])), tc[5], f1, false);
        e1 = __builtin_amdgcn_fdot2(habs2(hadd2u(wb1.z, xrp[6])), tc[6], e1, false);
        f1 = __builtin_amdgcn_fdot2(habs2(hadd2u(wb1.w, xrp[7])), tc[7], f1, false);
        float ep0 = e0 + f0;
        float ep1 = e1 + f1;
        ep0 += __shfl_xor(ep0, 1);                 // pair-merge (DPP)
        ep1 += __shfl_xor(ep1, 1);
        const float p0 = EXP2(ep0 + (u_b[2 * jp]     + negb));
        const float p1 = EXP2(ep1 + (u_b[2 * jp + 1] + negb));
        const h2 p01 = __builtin_bit_cast(h2, __builtin_amdgcn_cvt_pkrtz(p0, p1));
        h2 ones; ones.x = (_Float16)1.f; ones.y = (_Float16)1.f;
        l = __builtin_amdgcn_fdot2(p01, ones, l, false);
        const uint4* vp = (const uint4*)(xlt_b + (size_t)jp * 32 + dh * 16);
        const uint4 v0 = vp[0], v1 = vp[1], v2 = vp[2], v3 = vp[3];
        o[0]  = __builtin_amdgcn_fdot2(p01, u2h(v0.x), o[0],  false);
        o[1]  = __builtin_amdgcn_fdot2(p01, u2h(v0.y), o[1],  false);
        o[2]  = __builtin_amdgcn_fdot2(p01, u2h(v0.z), o[2],  false);
        o[3]  = __builtin_amdgcn_fdot2(p01, u2h(v0.w), o[3],  false);
        o[4]  = __builtin_amdgcn_fdot2(p01, u2h(v1.x), o[4],  false);
        o[5]  = __builtin_amdgcn_fdot2(p01, u2h(v1.y), o[5],  false);
        o[6]  = __builtin_amdgcn_fdot2(p01, u2h(v1.z), o[6],  false);
        o[7]  = __builtin_amdgcn_fdot2(p01, u2h(v1.w), o[7],  false);
        o[8]  = __builtin_amdgcn_fdot2(p01, u2h(v2.x), o[8],  false);
        o[9]  = __builtin_amdgcn_fdot2(p01, u2h(v2.y), o[9],  false);
        o[10] = __builtin_amdgcn_fdot2(p01, u2h(v2.z), o[10], false);
        o[11] = __builtin_amdgcn_fdot2(p01, u2h(v2.w), o[11], false);
        o[12] = __builtin_amdgcn_fdot2(p01, u2h(v3.x), o[12], false);
        o[13] = __builtin_amdgcn_fdot2(p01, u2h(v3.y), o[13], false);
        o[14] = __builtin_amdgcn_fdot2(p01, u2h(v3.z), o[14], false);
        o[15] = __builtin_amdgcn_fdot2(p01, u2h(v3.w), o[15], false);
    }

    float* Pp = P + (size_t)part * M_ + (size_t)row * D_ + dh * 16;
    #pragma unroll
    for (int k = 0; k < 4; k++) {
        v4f w;
        w.x = o[4*k]; w.y = o[4*k+1]; w.z = o[4*k+2]; w.w = o[4*k+3];
        ((v4f*)Pp)[k] = w;
    }
    if (dh == 0) lb[part * ROWS_ + row] = l;
}

// Fused: merge JS partials (shared bound -> sum(o)/sum(l)) + bias + LN(128)
// (+optional ReLU). One 64-thread block per node row (b,n).
template <int JS>
__global__ __launch_bounds__(64) void k_comb_ln(
    const float* __restrict__ P, const float* __restrict__ lb,
    const float* __restrict__ bias, const float* __restrict__ g,
    const float* __restrict__ bta, float* __restrict__ outp, int do_relu)
{
    const int row = blockIdx.x;                    // b*N+n
    const int b = row >> 11, n = row & (N_ - 1);
    const int t = threadIdx.x;
    const int c0 = t, c1 = t + 64;
    const int bh0 = b * H_ + (c0 >> 5), bh1 = b * H_ + (c1 >> 5);
    const size_t i0 = ((size_t)bh0 * N_ + n) * D_ + (c0 & 31);
    const size_t i1 = ((size_t)bh1 * N_ + n) * D_ + (c1 & 31);
    float a0 = 0.f, a1 = 0.f, L0 = 0.f, L1 = 0.f;
    #pragma unroll
    for (int s = 0; s < JS; s++) {
        a0 += P[(size_t)s * M_ + i0];
        a1 += P[(size_t)s * M_ + i1];
        L0 += lb[s * ROWS_ + bh0 * N_ + n];
        L1 += lb[s * ROWS_ + bh1 * N_ + n];
    }
    const float x0 = a0 / L0 + bias[c0];
    const float x1 = a1 / L1 + bias[c1];
    float s = x0 + x1;
    #pragma unroll
    for (int w = 1; w < 64; w <<= 1) s += __shfl_xor(s, w);
    const float mu = s * (1.f / 128.f);
    const float d0 = x0 - mu, d1 = x1 - mu;
    float q = d0 * d0 + d1 * d1;
    #pragma unroll
    for (int w = 1; w < 64; w <<= 1) q += __shfl_xor(q, w);
    const float rstd = rsqrtf(q * (1.f / 128.f) + 1e-5f);
    float y0 = d0 * rstd * g[c0] + bta[c0];
    float y1 = d1 * rstd * g[c1] + bta[c1];
    if (do_relu) { y0 = fmaxf(y0, 0.f); y1 = fmaxf(y1, 0.f); }
    outp[(size_t)row * HD_ + c0] = y0;
    outp[(size_t)row * HD_ + c1] = y1;
}

extern "C" void kernel_launch(void* const* d_in, const int* in_sizes, int n_in,
                              void* d_out, int out_size, void* d_ws, size_t ws_size,
                              hipStream_t stream) {
    const float* x    = (const float*)d_in[0];
    const float* Wl1  = (const float*)d_in[2];
    const float* bl1  = (const float*)d_in[3];
    const float* Wr1  = (const float*)d_in[4];
    const float* br1  = (const float*)d_in[5];
    const float* att1 = (const float*)d_in[6];
    const float* bias1= (const float*)d_in[7];
    const float* ln1g = (const float*)d_in[8];
    const float* ln1b = (const float*)d_in[9];
    const float* Wl2  = (const float*)d_in[10];
    const float* bl2  = (const float*)d_in[11];
    const float* Wr2  = (const float*)d_in[12];
    const float* br2  = (const float*)d_in[13];
    const float* att2 = (const float*)d_in[14];
    const float* bias2= (const float*)d_in[15];
    const float* ln2g = (const float*)d_in[16];
    const float* ln2b = (const float*)d_in[17];

    float* ws = (float*)d_ws;
    float* xl = ws;                                   // M_
    unsigned short* xlh = (unsigned short*)(xl + M_); // M_ halfs
    unsigned short* xrh = xlh + M_;                   // M_ halfs
    unsigned int* xlpT = (unsigned int*)(xrh + M_);   // M_/2 u32
    float* u     = xl + (size_t)(2.5 * M_);           // ROWS_
    float* bound = u + ROWS_;                         // ROWS_
    unsigned int* tch = (unsigned int*)(bound + ROWS_); // 64 u32

    // j-split: largest fitting. floats = 2.5M + 2R + 64 + js*(M+R) + M (h slab)
    int js = 1;
    for (int cand = 8; cand >= 1; cand >>= 1) {
        const size_t need = ((size_t)(3.5 * M_) + 2 * ROWS_ + 64
                             + (size_t)cand * (M_ + ROWS_)) * sizeof(float);
        if (ws_size >= need) { js = cand; break; }
    }
    const int jlen = N_ / js;

    float* P  = (float*)(tch + 64);        // js * M_
    float* lb = P + (size_t)js * M_;       // js * ROWS_
    float* h  = lb + (size_t)js * ROWS_;   // M_ (dedicated; P-slab alias races)
    float* outf = (float*)d_out;

    const int BN = B_ * N_;                // 8192
    // ---- layer 1 ----
    k_linear<<<BN / 32, 256, 0, stream>>>(x, Wl1, bl1, Wr1, br1, xl, xlh, xrh, xlpT, 32);
    k_u<<<ROWS_ / 256, 256, 0, stream>>>(xl, att1, u);
    k_bound<<<BH_, 512, 0, stream>>>((const unsigned int*)xlh, (const unsigned int*)xrh,
                                     u, att1, bound, tch);
    k_attn<<<256 * js, 256, 0, stream>>>((const unsigned int*)xlh, xlpT,
                                         (const unsigned int*)xrh, u, bound, tch, P, lb, jlen);
    if      (js == 8) k_comb_ln<8><<<BN, 64, 0, stream>>>(P, lb, bias1, ln1g, ln1b, h, 1);
    else if (js == 4) k_comb_ln<4><<<BN, 64, 0, stream>>>(P, lb, bias1, ln1g, ln1b, h, 1);
    else if (js == 2) k_comb_ln<2><<<BN, 64, 0, stream>>>(P, lb, bias1, ln1g, ln1b, h, 1);
    else              k_comb_ln<1><<<BN, 64, 0, stream>>>(P, lb, bias1, ln1g, ln1b, h, 1);
    // ---- layer 2 ----
    k_linear<<<BN / 32, 256, 0, stream>>>(h, Wl2, bl2, Wr2, br2, xl, xlh, xrh, xlpT, 128);
    k_u<<<ROWS_ / 256, 256, 0, stream>>>(xl, att2, u);
    k_bound<<<BH_, 512, 0, stream>>>((const unsigned int*)xlh, (const unsigned int*)xrh,
                                     u, att2, bound, tch);
    k_attn<<<256 * js, 256, 0, stream>>>((const unsigned int*)xlh, xlpT,
                                         (const unsigned int*)xrh, u, bound, tch, P, lb, jlen);
    if      (js == 8) k_comb_ln<8><<<BN, 64, 0, stream>>>(P, lb, bias2, ln2g, ln2b, outf, 0);
    else if (js == 4) k_comb_ln<4><<<BN, 64, 0, stream>>>(P, lb, bias2, ln2g, ln2b, outf, 0);
    else if (js == 2) k_comb_ln<2><<<BN, 64, 0, stream>>>(P, lb, bias2, ln2g, ln2b, outf, 0);
    else              k_comb_ln<1><<<BN, 64, 0, stream>>>(P, lb, bias2, ln2g, ln2b, outf, 0);
}

// Round 10
// 489.281 us; speedup vs baseline: 1.3609x; 1.3609x over previous
//
#include <hip/hip_runtime.h>
#include <math.h>

#define LOG2E 1.4426950408889634f

#if __has_builtin(__builtin_amdgcn_exp2f)
#define EXP2(x) __builtin_amdgcn_exp2f(x)
#else
#define EXP2(x) exp2f(x)
#endif

constexpr int B_ = 4, N_ = 2048, H_ = 4, D_ = 32, HD_ = 128;
constexpr int BH_ = B_ * H_;          // 16
constexpr int ROWS_ = BH_ * N_;       // 32768
constexpr size_t M_ = (size_t)ROWS_ * D_;  // 1,048,576 floats

typedef float v4f __attribute__((ext_vector_type(4)));
typedef _Float16 h2 __attribute__((ext_vector_type(2)));

static __device__ __forceinline__ h2 habs2(h2 z) {
    unsigned int t = __builtin_bit_cast(unsigned int, z) & 0x7FFF7FFFu;
    return __builtin_bit_cast(h2, t);
}
static __device__ __forceinline__ h2 hadd2u(unsigned int a, unsigned int b) {
    return __builtin_bit_cast(h2, a) + __builtin_bit_cast(h2, b);  // v_pk_add_f16
}
static __device__ __forceinline__ h2 u2h(unsigned int a) {
    return __builtin_bit_cast(h2, a);
}

// x[BN,K] @ Wl/Wr[K,128] + bl/br ->
//   xl   f32 [bh][n][d]      (k_u only)
//   xlh  f16 [bh][n][d]      (score)
//   xrh  f16 [bh][n][d]      (per-lane target rows)
//   xlpT f16 [bh][n/2][d]    (PV: j-pairs per d)
__global__ __launch_bounds__(256) void k_linear(
    const float* __restrict__ x,
    const float* __restrict__ Wl, const float* __restrict__ bl,
    const float* __restrict__ Wr, const float* __restrict__ br,
    float* __restrict__ xl, unsigned short* __restrict__ xlh,
    unsigned short* __restrict__ xrh, unsigned int* __restrict__ xlpT, int K)
{
    __shared__ __align__(16) float xs[32 * 128];
    const int tid = threadIdx.x;
    const int r0 = blockIdx.x * 32;
    const float4* src = (const float4*)(x + (size_t)r0 * K);
    float4* dst = (float4*)xs;
    for (int idx = tid; idx < 8 * K; idx += 256) dst[idx] = src[idx];
    __syncthreads();

    const int c  = tid & 127;
    const int rg = tid >> 7;
    float accl[16], accr[16];
    const float blv = bl[c], brv = br[c];
    #pragma unroll
    for (int r = 0; r < 16; r++) { accl[r] = blv; accr[r] = brv; }
    #pragma unroll 8
    for (int k = 0; k < K; k++) {
        const float wl = Wl[k * HD_ + c];
        const float wr = Wr[k * HD_ + c];
        #pragma unroll
        for (int r = 0; r < 16; r++) {
            const float xv = xs[(rg * 16 + r) * K + k];
            accl[r] = fmaf(xv, wl, accl[r]);
            accr[r] = fmaf(xv, wr, accr[r]);
        }
    }
    const int h = c >> 5, d = c & 31;
    #pragma unroll
    for (int r = 0; r < 16; r++) {
        const int row = r0 + rg * 16 + r;
        const int b = row >> 11, n = row & (N_ - 1);
        const size_t o = (((size_t)(b * H_ + h)) * N_ + n) * D_ + d;
        xl[o] = accl[r];
        xlh[o] = __builtin_bit_cast(unsigned short, (_Float16)accl[r]);
        xrh[o] = __builtin_bit_cast(unsigned short, (_Float16)accr[r]);
    }
    #pragma unroll
    for (int r = 0; r < 16; r += 2) {
        const int row = r0 + rg * 16 + r;
        const int b = row >> 11, n = row & (N_ - 1);
        h2 pr;
        pr.x = (_Float16)accl[r];
        pr.y = (_Float16)accl[r + 1];
        const size_t o = (((size_t)(b * H_ + h)) * (N_ / 2) + (n >> 1)) * D_ + d;
        xlpT[o] = __builtin_bit_cast(unsigned int, pr);
    }
}

// u_j = 0.6*log2e * att_h . xl_j  (target-side term cancels in softmax)
__global__ __launch_bounds__(256) void k_u(
    const float* __restrict__ xl, const float* __restrict__ att,
    float* __restrict__ u)
{
    const int idx = blockIdx.x * 256 + threadIdx.x; // [0, ROWS_)
    const int h = (idx / N_) & (H_ - 1);
    const float4* a4 = (const float4*)(att + h * D_);
    const float4* l4 = (const float4*)(xl + (size_t)idx * D_);
    float su = 0.f;
    #pragma unroll
    for (int q = 0; q < 8; q++) {
        const float4 a = a4[q], lv = l4[q];
        su += a.x * lv.x + a.y * lv.y + a.z * lv.z + a.w * lv.w;
    }
    u[idx] = 0.6f * LOG2E * su;
}

// Per-row sound upper bound on e (log2 domain); also packs tch.
__global__ __launch_bounds__(512) void k_bound(
    const unsigned int* __restrict__ xlh, const unsigned int* __restrict__ xrh,
    const float* __restrict__ u, const float* __restrict__ att,
    float* __restrict__ bound, unsigned int* __restrict__ tch)
{
    __shared__ float redA[16][33];
    __shared__ float redB[16][33];
    __shared__ float clv[32];
    __shared__ float tca[32];
    __shared__ float redu[512];
    const int bh = blockIdx.x, h = bh & (H_ - 1), t = threadIdx.x;

    if (bh < H_ && t < 16) {
        h2 v;
        v.x = (_Float16)(att[bh * D_ + 2 * t]     * (0.4f * LOG2E));
        v.y = (_Float16)(att[bh * D_ + 2 * t + 1] * (0.4f * LOG2E));
        tch[bh * 16 + t] = __builtin_bit_cast(unsigned int, v);
    }
    if (t < 16) {
        _Float16 a = (_Float16)(att[h * D_ + 2 * t]     * (0.4f * LOG2E));
        _Float16 b = (_Float16)(att[h * D_ + 2 * t + 1] * (0.4f * LOG2E));
        tca[2 * t]     = fabsf((float)a);
        tca[2 * t + 1] = fabsf((float)b);
    }
    const unsigned int* xb = xlh + (size_t)bh * N_ * 16;
    const int p = t & 15, rg = t >> 4;
    float m0 = 0.f, m1 = 0.f;
    for (int r = rg; r < N_; r += 32) {
        h2 z = __builtin_bit_cast(h2, xb[r * 16 + p] & 0x7FFF7FFFu);
        m0 = fmaxf(m0, (float)z.x);
        m1 = fmaxf(m1, (float)z.y);
    }
    redA[p][rg] = m0; redB[p][rg] = m1;
    const float* ub = u + (size_t)bh * N_;
    float um = -1e30f;
    for (int r = t; r < N_; r += 512) um = fmaxf(um, ub[r]);
    redu[t] = um;
    __syncthreads();
    if (t < 16) {
        float a = 0.f, b = 0.f;
        for (int g = 0; g < 32; g++) { a = fmaxf(a, redA[t][g]); b = fmaxf(b, redB[t][g]); }
        clv[2 * t] = a; clv[2 * t + 1] = b;
    }
    for (int s = 256; s > 0; s >>= 1) {
        if (t < s) redu[t] = fmaxf(redu[t], redu[t + s]);
        __syncthreads();
    }
    const float umax = redu[0];
    const unsigned int* xrb = xrh + (size_t)bh * N_ * 16;
    for (int r = t; r < N_; r += 512) {
        float s = 0.f;
        #pragma unroll
        for (int k = 0; k < 16; k++) {
            h2 z = __builtin_bit_cast(h2, xrb[r * 16 + k] & 0x7FFF7FFFu);
            s += tca[2 * k] * (clv[2 * k] + (float)z.x)
               + tca[2 * k + 1] * (clv[2 * k + 1] + (float)z.y);
        }
        bound[bh * N_ + r] = umax + s + 0.25f;
    }
}

// Flash GATv2 attention. Lane owns target row i (all 32 d's, no cross-lane).
// Fixed-bound softmax -> every j independent. PV via f16 j-pair fdot2.
// waves_per_eu(3,4): budget(3)=~170 regs > ~112 live -> NO AGPR shuttle
// (R6/R8/R9 disease: default allocator squeezes arch-VGPR to 32-36 and
// round-trips accumulators through AGPRs, ~2.5x instr inflation); max=4
// stops the occupancy-chasing squeeze at a 128-reg budget.
__global__ __launch_bounds__(256)
__attribute__((amdgpu_waves_per_eu(3, 4)))
void k_attn(
    const unsigned int* __restrict__ xlh,   // [bh][n][16] u32 (d-pairs)
    const unsigned int* __restrict__ xlpT,  // [bh][n/2][32] u32 (j-pairs)
    const unsigned int* __restrict__ xrh,
    const float* __restrict__ u, const float* __restrict__ bound,
    const unsigned int* __restrict__ tch,
    float* __restrict__ P, float* __restrict__ lb, int jlen)
{
    const int tid = threadIdx.x, lane = tid & 63, wid = tid >> 6;
    const int t128 = blockIdx.x & 127, part = blockIdx.x >> 7;
    const int bh = t128 >> 3;
    const int h  = bh & (H_ - 1);
    const int row = bh * N_ + (t128 & 7) * 256 + wid * 64 + lane;

    // wave-uniform score coefficients -> SGPRs (VOP3P allows one SGPR src)
    unsigned int tcs[16];
    #pragma unroll
    for (int k = 0; k < 16; k++)
        tcs[k] = __builtin_amdgcn_readfirstlane(tch[h * 16 + k]);

    unsigned int xrp[16];
    {
        const uint4* s = (const uint4*)(xrh + (size_t)row * 16);
        const uint4 a = s[0], b = s[1], c = s[2], d = s[3];
        xrp[0]=a.x; xrp[1]=a.y; xrp[2]=a.z; xrp[3]=a.w;
        xrp[4]=b.x; xrp[5]=b.y; xrp[6]=b.z; xrp[7]=b.w;
        xrp[8]=c.x; xrp[9]=c.y; xrp[10]=c.z; xrp[11]=c.w;
        xrp[12]=d.x; xrp[13]=d.y; xrp[14]=d.z; xrp[15]=d.w;
    }
    const float negb = -bound[row];

    float l = 0.f;
    float o[32];
    #pragma unroll
    for (int k = 0; k < 32; k++) o[k] = 0.f;

    const unsigned int* xlh_b = xlh + (size_t)bh * N_ * 16;
    const unsigned int* xlt_b = xlpT + (size_t)bh * (N_ / 2) * 32;
    const float* u_b = u + (size_t)bh * N_;

    const int jpb = (part * jlen) >> 1, jpe = jpb + (jlen >> 1);
    for (int jp = jpb; jp < jpe; jp++) {
        const unsigned int* w0 = xlh_b + (size_t)(2 * jp) * 16;  // row j0 (uniform)
        const unsigned int* w1 = w0 + 16;                        // row j1 (uniform)
        float e0 = u_b[2 * jp]     + negb;
        float f0 = 0.f, e1 = u_b[2 * jp + 1] + negb, f1 = 0.f;
        #pragma unroll
        for (int k = 0; k < 16; k += 2) {
            e0 = __builtin_amdgcn_fdot2(habs2(hadd2u(w0[k],     xrp[k])),     u2h(tcs[k]),     e0, false);
            f0 = __builtin_amdgcn_fdot2(habs2(hadd2u(w0[k + 1], xrp[k + 1])), u2h(tcs[k + 1]), f0, false);
            e1 = __builtin_amdgcn_fdot2(habs2(hadd2u(w1[k],     xrp[k])),     u2h(tcs[k]),     e1, false);
            f1 = __builtin_amdgcn_fdot2(habs2(hadd2u(w1[k + 1], xrp[k + 1])), u2h(tcs[k + 1]), f1, false);
        }
        const float p0 = EXP2(e0 + f0);
        const float p1 = EXP2(e1 + f1);
        const h2 p01 = __builtin_bit_cast(h2, __builtin_amdgcn_cvt_pkrtz(p0, p1));
        h2 ones; ones.x = (_Float16)1.f; ones.y = (_Float16)1.f;
        l = __builtin_amdgcn_fdot2(p01, ones, l, false);
        const unsigned int* vp = xlt_b + (size_t)jp * 32;        // uniform
        #pragma unroll
        for (int d = 0; d < 32; d++)
            o[d] = __builtin_amdgcn_fdot2(p01, u2h(vp[d]), o[d], false);
    }

    float* Pp = P + (size_t)part * M_ + (size_t)row * D_;
    #pragma unroll
    for (int k = 0; k < 8; k++) {
        v4f w;
        w.x = o[4*k]; w.y = o[4*k+1]; w.z = o[4*k+2]; w.w = o[4*k+3];
        ((v4f*)Pp)[k] = w;
    }
    lb[part * ROWS_ + row] = l;
}

// Fused: merge JS partials (shared bound -> sum(o)/sum(l)) + bias + LN(128)
// (+optional ReLU). One 64-thread block per node row (b,n).
template <int JS>
__global__ __launch_bounds__(64) void k_comb_ln(
    const float* __restrict__ P, const float* __restrict__ lb,
    const float* __restrict__ bias, const float* __restrict__ g,
    const float* __restrict__ bta, float* __restrict__ outp, int do_relu)
{
    const int row = blockIdx.x;                    // b*N+n
    const int b = row >> 11, n = row & (N_ - 1);
    const int t = threadIdx.x;
    const int c0 = t, c1 = t + 64;
    const int bh0 = b * H_ + (c0 >> 5), bh1 = b * H_ + (c1 >> 5);
    const size_t i0 = ((size_t)bh0 * N_ + n) * D_ + (c0 & 31);
    const size_t i1 = ((size_t)bh1 * N_ + n) * D_ + (c1 & 31);
    float a0 = 0.f, a1 = 0.f, L0 = 0.f, L1 = 0.f;
    #pragma unroll
    for (int s = 0; s < JS; s++) {
        a0 += P[(size_t)s * M_ + i0];
        a1 += P[(size_t)s * M_ + i1];
        L0 += lb[s * ROWS_ + bh0 * N_ + n];
        L1 += lb[s * ROWS_ + bh1 * N_ + n];
    }
    const float x0 = a0 / L0 + bias[c0];
    const float x1 = a1 / L1 + bias[c1];
    float s = x0 + x1;
    #pragma unroll
    for (int w = 1; w < 64; w <<= 1) s += __shfl_xor(s, w);
    const float mu = s * (1.f / 128.f);
    const float d0 = x0 - mu, d1 = x1 - mu;
    float q = d0 * d0 + d1 * d1;
    #pragma unroll
    for (int w = 1; w < 64; w <<= 1) q += __shfl_xor(q, w);
    const float rstd = rsqrtf(q * (1.f / 128.f) + 1e-5f);
    float y0 = d0 * rstd * g[c0] + bta[c0];
    float y1 = d1 * rstd * g[c1] + bta[c1];
    if (do_relu) { y0 = fmaxf(y0, 0.f); y1 = fmaxf(y1, 0.f); }
    outp[(size_t)row * HD_ + c0] = y0;
    outp[(size_t)row * HD_ + c1] = y1;
}

extern "C" void kernel_launch(void* const* d_in, const int* in_sizes, int n_in,
                              void* d_out, int out_size, void* d_ws, size_t ws_size,
                              hipStream_t stream) {
    const float* x    = (const float*)d_in[0];
    const float* Wl1  = (const float*)d_in[2];
    const float* bl1  = (const float*)d_in[3];
    const float* Wr1  = (const float*)d_in[4];
    const float* br1  = (const float*)d_in[5];
    const float* att1 = (const float*)d_in[6];
    const float* bias1= (const float*)d_in[7];
    const float* ln1g = (const float*)d_in[8];
    const float* ln1b = (const float*)d_in[9];
    const float* Wl2  = (const float*)d_in[10];
    const float* bl2  = (const float*)d_in[11];
    const float* Wr2  = (const float*)d_in[12];
    const float* br2  = (const float*)d_in[13];
    const float* att2 = (const float*)d_in[14];
    const float* bias2= (const float*)d_in[15];
    const float* ln2g = (const float*)d_in[16];
    const float* ln2b = (const float*)d_in[17];

    float* ws = (float*)d_ws;
    float* xl = ws;                                   // M_
    unsigned short* xlh = (unsigned short*)(xl + M_); // M_ halfs
    unsigned short* xrh = xlh + M_;                   // M_ halfs
    unsigned int* xlpT = (unsigned int*)(xrh + M_);   // M_/2 u32
    float* u     = xl + (size_t)(2.5 * M_);           // ROWS_
    float* bound = u + ROWS_;                         // ROWS_
    unsigned int* tch = (unsigned int*)(bound + ROWS_); // 64 u32

    // j-split: largest fitting. floats = 2.5M + 2R + 64 + js*(M+R) + M (h slab)
    int js = 1;
    for (int cand = 8; cand >= 1; cand >>= 1) {
        const size_t need = ((size_t)(3.5 * M_) + 2 * ROWS_ + 64
                             + (size_t)cand * (M_ + ROWS_)) * sizeof(float);
        if (ws_size >= need) { js = cand; break; }
    }
    const int jlen = N_ / js;

    float* P  = (float*)(tch + 64);        // js * M_
    float* lb = P + (size_t)js * M_;       // js * ROWS_
    float* h  = lb + (size_t)js * ROWS_;   // M_ (dedicated slab)
    float* outf = (float*)d_out;

    const int BN = B_ * N_;                // 8192
    // ---- layer 1 ----
    k_linear<<<BN / 32, 256, 0, stream>>>(x, Wl1, bl1, Wr1, br1, xl, xlh, xrh, xlpT, 32);
    k_u<<<ROWS_ / 256, 256, 0, stream>>>(xl, att1, u);
    k_bound<<<BH_, 512, 0, stream>>>((const unsigned int*)xlh, (const unsigned int*)xrh,
                                     u, att1, bound, tch);
    k_attn<<<128 * js, 256, 0, stream>>>((const unsigned int*)xlh, xlpT,
                                         (const unsigned int*)xrh, u, bound, tch, P, lb, jlen);
    if      (js == 8) k_comb_ln<8><<<BN, 64, 0, stream>>>(P, lb, bias1, ln1g, ln1b, h, 1);
    else if (js == 4) k_comb_ln<4><<<BN, 64, 0, stream>>>(P, lb, bias1, ln1g, ln1b, h, 1);
    else if (js == 2) k_comb_ln<2><<<BN, 64, 0, stream>>>(P, lb, bias1, ln1g, ln1b, h, 1);
    else              k_comb_ln<1><<<BN, 64, 0, stream>>>(P, lb, bias1, ln1g, ln1b, h, 1);
    // ---- layer 2 ----
    k_linear<<<BN / 32, 256, 0, stream>>>(h, Wl2, bl2, Wr2, br2, xl, xlh, xrh, xlpT, 128);
    k_u<<<ROWS_ / 256, 256, 0, stream>>>(xl, att2, u);
    k_bound<<<BH_, 512, 0, stream>>>((const unsigned int*)xlh, (const unsigned int*)xrh,
                                     u, att2, bound, tch);
    k_attn<<<128 * js, 256, 0, stream>>>((const unsigned int*)xlh, xlpT,
                                         (const unsigned int*)xrh, u, bound, tch, P, lb, jlen);
    if      (js == 8) k_comb_ln<8><<<BN, 64, 0, stream>>>(P, lb, bias2, ln2g, ln2b, outf, 0);
    else if (js == 4) k_comb_ln<4><<<BN, 64, 0, stream>>>(P, lb, bias2, ln2g, ln2b, outf, 0);
    else if (js == 2) k_comb_ln<2><<<BN, 64, 0, stream>>>(P, lb, bias2, ln2g, ln2b, outf, 0);
    else              k_comb_ln<1><<<BN, 64, 0, stream>>>(P, lb, bias2, ln2g, ln2b, outf, 0);
}